// Round 6
// baseline (2297.538 us; speedup 1.0000x reference)
//
#include <hip/hip_runtime.h>

// ---- problem constants ----
#define Hdim 2048
#define Idim 5632
#define NEXP 8
#define NTOK 8192          // B*S = 4*2048
#define NROW 16384         // NTOK * top_k
#define RCAP 18432         // 72 tiles * 256 (max padded rows, 256-align per expert)
#define MT256 72

// ---- workspace meta layout (int indices) ----
#define MI_NTILES   0      // number of 256-row M tiles
#define MI_TOTAL    1
#define MI_COUNT    2      // [8]
#define MI_CURSOR   10     // [8]
#define MI_OFF      18     // [9]
#define MI_TILEEXP  32     // [72]
#define MI_ROWTOK   128    // [18432] token index per gathered row
#define MI_ROWW     18560  // [18432] float weight per gathered row
#define MI_TOPKID   36992  // [16384]
#define MI_TOPKW    53376  // [16384] floats
#define META_ZERO_BYTES (36992u * 4u)   // zero counts..row_weight each call

// ---- workspace buffer layout (byte offsets) ----
// Xg  bf16 [RCAP][Hdim]      = 72 MiB
// WgT bf16 [E][Idim][Hdim]   = 176 MiB (transposed)  -- WdT aliases this after gateup
// WuT bf16 [E][Idim][Hdim]   = 176 MiB
// Hbuf bf16 [RCAP][Idim]     = 198 MiB
#define XG_OFF   (1ull << 19)
#define WGT_OFF  (73ull  << 20)
#define WUT_OFF  (249ull << 20)
#define HB_OFF   (425ull << 20)
#define WDT_OFF  WGT_OFF

typedef __attribute__((ext_vector_type(8))) short s8v;   // 8 bf16 = 4 VGPR
typedef __attribute__((ext_vector_type(4))) float f4v;   // MFMA acc

#define BAR()  asm volatile("s_barrier" ::: "memory")
#define VMW2() asm volatile("s_waitcnt vmcnt(2)" ::: "memory")

__device__ __forceinline__ unsigned short f2bf(float f) {  // RNE
  unsigned int u = __float_as_uint(f);
  u += 0x7fffu + ((u >> 16) & 1u);
  return (unsigned short)(u >> 16);
}
__device__ __forceinline__ unsigned int pack2(float lo, float hi) { // truncate, 2 bf16 in 1 dword
  return (__float_as_uint(lo) >> 16) | (__float_as_uint(hi) & 0xffff0000u);
}
__device__ __forceinline__ void glds16(const short* gp, short* lp) {
  __builtin_amdgcn_global_load_lds(
      (const __attribute__((address_space(1))) void*)gp,
      (__attribute__((address_space(3))) void*)lp, 16, 0, 0);
}

// ---------------- router ----------------
__global__ __launch_bounds__(256) void router_kernel(
    const float* __restrict__ x, const float* __restrict__ Wr,
    const float* __restrict__ br, float* __restrict__ logits,
    int* __restrict__ meta)
{
  int wv = threadIdx.x >> 6, lane = threadIdx.x & 63;
  int t = blockIdx.x * 4 + wv;
  const float* xr = x + (size_t)t * Hdim;
  float acc[8];
#pragma unroll
  for (int e = 0; e < 8; ++e) acc[e] = 0.f;
  for (int i = lane; i < Hdim; i += 64) {
    float xv = xr[i];
    const float4 w0 = *(const float4*)(Wr + (size_t)i * 8);
    const float4 w1 = *(const float4*)(Wr + (size_t)i * 8 + 4);
    acc[0] += xv * w0.x; acc[1] += xv * w0.y; acc[2] += xv * w0.z; acc[3] += xv * w0.w;
    acc[4] += xv * w1.x; acc[5] += xv * w1.y; acc[6] += xv * w1.z; acc[7] += xv * w1.w;
  }
#pragma unroll
  for (int off = 32; off > 0; off >>= 1)
#pragma unroll
    for (int e = 0; e < 8; ++e) acc[e] += __shfl_down(acc[e], off);
  if (lane == 0) {
    float l[8];
#pragma unroll
    for (int e = 0; e < 8; ++e) { l[e] = acc[e] + br[e]; logits[(size_t)t * 8 + e] = l[e]; }
    int i1 = 0;
#pragma unroll
    for (int e = 1; e < 8; ++e) if (l[e] > l[i1]) i1 = e;
    int i2 = -1;
#pragma unroll
    for (int e = 0; e < 8; ++e) if (e != i1 && (i2 < 0 || l[e] > l[i2])) i2 = e;
    float p2 = __expf(l[i2] - l[i1]);
    float s = 1.f + p2;
    meta[MI_TOPKID + t * 2]     = i1;
    meta[MI_TOPKID + t * 2 + 1] = i2;
    float* tw = (float*)(meta + MI_TOPKW);
    tw[t * 2] = 1.f / s; tw[t * 2 + 1] = p2 / s;
    atomicAdd(&meta[MI_COUNT + i1], 1);
    atomicAdd(&meta[MI_COUNT + i2], 1);
  }
}

// ---------------- offsets: 256-aligned expert segments ----------------
__global__ void offsets_kernel(int* __restrict__ meta)
{
  __shared__ int soff[9];
  if (threadIdx.x == 0) {
    int off = 0;
#pragma unroll
    for (int e = 0; e < 8; ++e) {
      soff[e] = off;
      meta[MI_OFF + e] = off;
      meta[MI_CURSOR + e] = off;
      int c = meta[MI_COUNT + e];
      off += (c + 255) & ~255;
    }
    soff[8] = off;
    meta[MI_OFF + 8] = off;
    meta[MI_TOTAL] = off;
    meta[MI_NTILES] = off >> 8;
  }
  __syncthreads();
  int tile = threadIdx.x;
  if (tile < MT256) {
    int r = tile << 8;
    int e = 7;
    for (int q = 7; q >= 0; --q) if (r < soff[q + 1]) e = q;
    meta[MI_TILEEXP + tile] = e;
  }
}

// ---------------- scatter ----------------
__global__ __launch_bounds__(256) void scatter_kernel(int* __restrict__ meta)
{
  int idx = blockIdx.x * 256 + threadIdx.x;           // < 16384
  int e = meta[MI_TOPKID + idx];
  float w = ((const float*)(meta + MI_TOPKW))[idx];
  int pos = atomicAdd(&meta[MI_CURSOR + e], 1);
  meta[MI_ROWTOK + pos] = idx >> 1;
  ((float*)(meta + MI_ROWW))[pos] = w;
}

// ---------------- gather: x rows -> bf16 Xg in expert order ----------------
__global__ __launch_bounds__(256) void gather_kernel(
    const float* __restrict__ x, short* __restrict__ Xg,
    const int* __restrict__ meta)
{
  int r = blockIdx.x;
  int tok = meta[MI_ROWTOK + r];                       // 0 for pad rows (weight 0)
  int i = threadIdx.x * 8;
  const float* src = x + (size_t)tok * Hdim + i;
  float4 a = *(const float4*)src;
  float4 b = *(const float4*)(src + 4);
  union { s8v v; unsigned short us[8]; } o;
  o.us[0] = f2bf(a.x); o.us[1] = f2bf(a.y); o.us[2] = f2bf(a.z); o.us[3] = f2bf(a.w);
  o.us[4] = f2bf(b.x); o.us[5] = f2bf(b.y); o.us[6] = f2bf(b.z); o.us[7] = f2bf(b.w);
  *(s8v*)(Xg + (size_t)r * Hdim + i) = o.v;
}

// ---------------- transpose-convert: T[e][n][k] (bf16) = W[e][k][n] (fp32) ----------------
__global__ __launch_bounds__(256) void convT_kernel(
    const float* __restrict__ W, short* __restrict__ T, int K, int N)
{
  __shared__ float lds[64][65];
  int ntn = N >> 6, ntk = K >> 6;
  int per_e = ntn * ntk;
  int e = blockIdx.x / per_e;
  int r = blockIdx.x % per_e;
  int tn = r % ntn, tk = r / ntn;
  const float* We = W + (size_t)e * K * N;
  short* Te = T + (size_t)e * K * N;
  int n0 = tn << 6, k0 = tk << 6;
  int tid = threadIdx.x;
  int c = tid & 63, rr = tid >> 6;
#pragma unroll
  for (int i = 0; i < 16; ++i) {
    int k = i * 4 + rr;
    lds[c][k] = We[(size_t)(k0 + k) * N + n0 + c];
  }
  __syncthreads();
  int kp = tid & 31, nb = tid >> 5;
#pragma unroll
  for (int i = 0; i < 8; ++i) {
    int n = i * 8 + nb;
    float2 f = *(const float2*)&lds[n][kp * 2];
    unsigned int u = pack2(f.x, f.y);
    *(unsigned int*)((char*)Te + ((size_t)(n0 + n) * K + k0) * 2 + kp * 4) = u;
  }
}

// ======== 8-phase GEMM kernels: BM=256, BK=64, 512 threads (8 waves 4Mx2N) ========
// LDS tiles row-major [row][64] bf16 (128B rows), XOR slot swizzle:
//   phys 16B slot j' = j ^ (row&7); glds dest linear, SOURCE pre-swizzled, reads swizzled.
// Per K-tile: 4 phases {ds_read | 1 prefetch chunk | bar | setprio | 16(8) MFMA | bar}.
// Prefetch: chunks of tile t+1 at P1..P3(+prev P4); A0(t+2) at P4; s_waitcnt vmcnt(2) at P4.

// issue one chunk = 2 glds rounds (64 rows each); pX includes rowoff+kc swizzle
#define ISSUE_A2(buf, h, kt) do { size_t kk_ = (size_t)(kt) * 64;                          \
  glds16(pA + (size_t)((h) * 128      ) * strideA + kk_, &sA[(buf)][(h) * 8192 + ldst]);   \
  glds16(pA + (size_t)((h) * 128 + 64 ) * strideA + kk_, &sA[(buf)][(h) * 8192 + 4096 + ldst]); } while (0)
#define ISSUE_B2(arr, pB, buf, kt) do { size_t kk_ = (size_t)(kt) * 64;                    \
  glds16((pB) + kk_,                          &arr[(buf)][ldst]);                          \
  glds16((pB) + (size_t)64 * strideA + kk_,   &arr[(buf)][4096 + ldst]); } while (0)

// ---------------- pass A: h = silu(Xg@Wg[e]) * (Xg@Wu[e]) -> bf16 Hbuf ----------------
// BN=128, dual accumulator (gate+up). LDS: A 64K + G 32K + U 32K = 128 KiB.
__global__ __launch_bounds__(512, 2) void gateup_kernel(
    const short* __restrict__ Xg, const short* __restrict__ WgT,
    const short* __restrict__ WuT, short* __restrict__ Hbuf,
    const int* __restrict__ meta)
{
  const int NT = Idim / 128;                 // 44
  int wg = (blockIdx.x & 7) * (MT256 / 8 * NT) + (blockIdx.x >> 3);  // XCD-bijective
  int chunk = wg / (8 * NT);
  int rem   = wg % (8 * NT);
  int mtile = chunk * 8 + (rem & 7);
  int ntile = rem >> 3;
  if (mtile >= meta[MI_NTILES]) return;
  int e = meta[MI_TILEEXP + mtile];
  int n0 = ntile * 128;
  const size_t strideA = Hdim;

  __shared__ short sA[2][16384];             // 256 x 64
  __shared__ short sG[2][8192];              // 128 x 64
  __shared__ short sU[2][8192];

  int tid = threadIdx.x;
  int lane = tid & 63, wv = tid >> 6;
  int wm = wv >> 1, wn = wv & 1;             // wm in [0,4): 64 A-rows; wn in [0,2): 64 B-rows
  int lr = lane & 15, lg = lane >> 4;
  int ldst = wv * 512;                       // wave-uniform LDS dest (shorts)

  // staging source: row = tid>>3 (within 64-row round), pre-swizzled k-slot
  int srow = tid >> 3;
  int kc = ((tid & 7) ^ (srow & 7)) * 8;
  const short* pA = Xg  + (size_t)(mtile * 256) * Hdim + (size_t)srow * Hdim + kc;
  const short* pG = WgT + (size_t)e * Idim * Hdim + (size_t)(n0 + srow) * Hdim + kc;
  const short* pU = WuT + (size_t)e * Idim * Hdim + (size_t)(n0 + srow) * Hdim + kc;

  // swizzled fragment offsets (shorts): row*64 + ((ks*4+lg)^(row&7))*8
  int aoff[4][2], boff[4][2];
#pragma unroll
  for (int mi = 0; mi < 4; ++mi) {
    int R = wm * 64 + mi * 16 + lr;
#pragma unroll
    for (int ks = 0; ks < 2; ++ks) aoff[mi][ks] = R * 64 + (((ks * 4 + lg) ^ (R & 7)) << 3);
  }
#pragma unroll
  for (int ni = 0; ni < 4; ++ni) {
    int R = wn * 64 + ni * 16 + lr;
#pragma unroll
    for (int ks = 0; ks < 2; ++ks) boff[ni][ks] = R * 64 + (((ks * 4 + lg) ^ (R & 7)) << 3);
  }

  f4v AG[4][4], AU[4][4];
  f4v z = {0.f, 0.f, 0.f, 0.f};
#pragma unroll
  for (int a1 = 0; a1 < 4; ++a1)
#pragma unroll
    for (int b1 = 0; b1 < 4; ++b1) { AG[a1][b1] = z; AU[a1][b1] = z; }

  const int NKT = Hdim / 64;                 // 32 (even)

  // prologue: tile0 -> buf0 (8 loads), A0(tile1) -> buf1 (2 loads)
  ISSUE_A2(0, 0, 0); ISSUE_A2(0, 1, 0);
  ISSUE_B2(sG, pG, 0, 0); ISSUE_B2(sU, pU, 0, 0);
  ISSUE_A2(1, 0, 1);
  VMW2(); BAR();

#define GU_HALF(CUR, T)                                                                    \
  do {                                                                                     \
    int nx1 = (T) + 1; if (nx1 >= NKT) nx1 -= NKT;                                         \
    int nx2 = (T) + 2; if (nx2 >= NKT) nx2 -= NKT;                                         \
    s8v a_[4][2], g0_[2][2], g1_[2][2], u0_[2][2], u1_[2][2];                              \
    /* P1: read a + gate nh0; issue A1(t+1) */                                             \
    _Pragma("unroll") for (int mi = 0; mi < 4; ++mi)                                       \
      _Pragma("unroll") for (int ks = 0; ks < 2; ++ks)                                     \
        a_[mi][ks] = *(const s8v*)&sA[CUR][aoff[mi][ks]];                                  \
    _Pragma("unroll") for (int ni = 0; ni < 2; ++ni)                                       \
      _Pragma("unroll") for (int ks = 0; ks < 2; ++ks)                                     \
        g0_[ni][ks] = *(const s8v*)&sG[CUR][boff[ni][ks]];                                 \
    ISSUE_A2((CUR) ^ 1, 1, nx1);                                                           \
    BAR(); __builtin_amdgcn_s_setprio(1);                                                  \
    _Pragma("unroll") for (int mi = 0; mi < 4; ++mi)                                       \
      _Pragma("unroll") for (int ni = 0; ni < 2; ++ni)                                     \
        _Pragma("unroll") for (int ks = 0; ks < 2; ++ks)                                   \
          AG[mi][ni] = __builtin_amdgcn_mfma_f32_16x16x32_bf16(a_[mi][ks], g0_[ni][ks],    \
                                                               AG[mi][ni], 0, 0, 0);       \
    __builtin_amdgcn_s_setprio(0); BAR();                                                  \
    /* P2: read gate nh1 + up nh0; issue G(t+1) */                                         \
    _Pragma("unroll") for (int ni = 0; ni < 2; ++ni)                                       \
      _Pragma("unroll") for (int ks = 0; ks < 2; ++ks) {                                   \
        g1_[ni][ks] = *(const s8v*)&sG[CUR][boff[2 + ni][ks]];                             \
        u0_[ni][ks] = *(const s8v*)&sU[CUR][boff[ni][ks]];                                 \
      }                                                                                    \
    ISSUE_B2(sG, pG, (CUR) ^ 1, nx1);                                                      \
    BAR(); __builtin_amdgcn_s_setprio(1);                                                  \
    _Pragma("unroll") for (int mi = 0; mi < 4; ++mi)                                       \
      _Pragma("unroll") for (int ni = 0; ni < 2; ++ni)                                     \
        _Pragma("unroll") for (int ks = 0; ks < 2; ++ks)                                   \
          AG[mi][2 + ni] = __builtin_amdgcn_mfma_f32_16x16x32_bf16(a_[mi][ks], g1_[ni][ks],\
                                                                   AG[mi][2 + ni], 0, 0, 0);\
    __builtin_amdgcn_s_setprio(0); BAR();                                                  \
    /* P3: read up nh1; issue U(t+1); MFMA up nh0 */                                       \
    _Pragma("unroll") for (int ni = 0; ni < 2; ++ni)                                       \
      _Pragma("unroll") for (int ks = 0; ks < 2; ++ks)                                     \
        u1_[ni][ks] = *(const s8v*)&sU[CUR][boff[2 + ni][ks]];                             \
    ISSUE_B2(sU, pU, (CUR) ^ 1, nx1);                                                      \
    BAR(); __builtin_amdgcn_s_setprio(1);                                                  \
    _Pragma("unroll") for (int mi = 0; mi < 4; ++mi)                                       \
      _Pragma("unroll") for (int ni = 0; ni < 2; ++ni)                                     \
        _Pragma("unroll") for (int ks = 0; ks < 2; ++ks)                                   \
          AU[mi][ni] = __builtin_amdgcn_mfma_f32_16x16x32_bf16(a_[mi][ks], u0_[ni][ks],    \
                                                               AU[mi][ni], 0, 0, 0);       \
    __builtin_amdgcn_s_setprio(0); BAR();                                                  \
    /* P4: issue A0(t+2); counted wait; MFMA up nh1 */                                     \
    ISSUE_A2(CUR, 0, nx2);                                                                 \
    VMW2();                                                                                \
    BAR(); __builtin_amdgcn_s_setprio(1);                                                  \
    _Pragma("unroll") for (int mi = 0; mi < 4; ++mi)                                       \
      _Pragma("unroll") for (int ni = 0; ni < 2; ++ni)                                     \
        _Pragma("unroll") for (int ks = 0; ks < 2; ++ks)                                   \
          AU[mi][2 + ni] = __builtin_amdgcn_mfma_f32_16x16x32_bf16(a_[mi][ks], u1_[ni][ks],\
                                                                   AU[mi][2 + ni], 0, 0, 0);\
    __builtin_amdgcn_s_setprio(0); BAR();                                                  \
  } while (0)

  for (int t = 0; t < NKT; t += 2) {
    GU_HALF(0, t);
    GU_HALF(1, t + 1);
  }
#undef GU_HALF

  // epilogue: h = silu(g)*u -> bf16  (C/D: col=lane&15, row=(lane>>4)*4+r)
  int row0 = mtile * 256 + wm * 64;
  int col0 = n0 + wn * 64;
#pragma unroll
  for (int mi = 0; mi < 4; ++mi) {
#pragma unroll
    for (int ni = 0; ni < 4; ++ni) {
      int col = col0 + ni * 16 + lr;
#pragma unroll
      for (int r = 0; r < 4; ++r) {
        int row = row0 + mi * 16 + lg * 4 + r;
        float g = AG[mi][ni][r], u = AU[mi][ni][r];
        float h = g / (1.f + __expf(-g)) * u;
        Hbuf[(size_t)row * Idim + col] = (short)f2bf(h);
      }
    }
  }
}

// ---------------- pass B: y = Hbuf@Wd[e]; out[token] += w*y (atomic) ----------------
// BN=128 single matrix. LDS: A 64K + B 32K = 96 KiB.
__global__ __launch_bounds__(512, 2) void down_kernel(
    const short* __restrict__ Hbuf, const short* __restrict__ WdT,
    float* __restrict__ out, const int* __restrict__ meta)
{
  const int NT = Hdim / 128;                 // 16
  int wg = (blockIdx.x & 7) * (MT256 / 8 * NT) + (blockIdx.x >> 3);
  int chunk = wg / (8 * NT);
  int rem   = wg % (8 * NT);
  int mtile = chunk * 8 + (rem & 7);
  int ntile = rem >> 3;
  if (mtile >= meta[MI_NTILES]) return;
  int e = meta[MI_TILEEXP + mtile];
  int n0 = ntile * 128;
  const size_t strideA = Idim;

  __shared__ short sA[2][16384];
  __shared__ short sB[2][8192];

  int tid = threadIdx.x;
  int lane = tid & 63, wv = tid >> 6;
  int wm = wv >> 1, wn = wv & 1;
  int lr = lane & 15, lg = lane >> 4;
  int ldst = wv * 512;

  int srow = tid >> 3;
  int kc = ((tid & 7) ^ (srow & 7)) * 8;
  const short* pA = Hbuf + (size_t)(mtile * 256) * Idim + (size_t)srow * Idim + kc;
  const short* pB = WdT  + (size_t)e * Hdim * Idim + (size_t)(n0 + srow) * Idim + kc;

  int aoff[4][2], boff[4][2];
#pragma unroll
  for (int mi = 0; mi < 4; ++mi) {
    int R = wm * 64 + mi * 16 + lr;
#pragma unroll
    for (int ks = 0; ks < 2; ++ks) aoff[mi][ks] = R * 64 + (((ks * 4 + lg) ^ (R & 7)) << 3);
  }
#pragma unroll
  for (int ni = 0; ni < 4; ++ni) {
    int R = wn * 64 + ni * 16 + lr;
#pragma unroll
    for (int ks = 0; ks < 2; ++ks) boff[ni][ks] = R * 64 + (((ks * 4 + lg) ^ (R & 7)) << 3);
  }

  f4v AC[4][4];
  f4v z = {0.f, 0.f, 0.f, 0.f};
#pragma unroll
  for (int a1 = 0; a1 < 4; ++a1)
#pragma unroll
    for (int b1 = 0; b1 < 4; ++b1) AC[a1][b1] = z;

  const int NKT = Idim / 64;                 // 88 (even)

  ISSUE_A2(0, 0, 0); ISSUE_A2(0, 1, 0);
  ISSUE_B2(sB, pB, 0, 0);
  ISSUE_A2(1, 0, 1);
  VMW2(); BAR();

#define DN_PHASE(CUR, NI, EXTRA)                                                           \
  do {                                                                                     \
    EXTRA;                                                                                 \
    BAR(); __builtin_amdgcn_s_setprio(1);                                                  \
    _Pragma("unroll") for (int mi = 0; mi < 4; ++mi)                                       \
      _Pragma("unroll") for (int ks = 0; ks < 2; ++ks)                                     \
        AC[mi][NI] = __builtin_amdgcn_mfma_f32_16x16x32_bf16(a_[mi][ks], b_[NI][ks],       \
                                                             AC[mi][NI], 0, 0, 0);         \
    __builtin_amdgcn_s_setprio(0); BAR();                                                  \
  } while (0)

#define DN_HALF(CUR, T)                                                                    \
  do {                                                                                     \
    int nx1 = (T) + 1; if (nx1 >= NKT) nx1 -= NKT;                                         \
    int nx2 = (T) + 2; if (nx2 >= NKT) nx2 -= NKT;                                         \
    s8v a_[4][2], b_[4][2];                                                                \
    /* P1 reads: a + b[0..1] */                                                            \
    _Pragma("unroll") for (int mi = 0; mi < 4; ++mi)                                       \
      _Pragma("unroll") for (int ks = 0; ks < 2; ++ks)                                     \
        a_[mi][ks] = *(const s8v*)&sA[CUR][aoff[mi][ks]];                                  \
    _Pragma("unroll") for (int ni = 0; ni < 2; ++ni)                                       \
      _Pragma("unroll") for (int ks = 0; ks < 2; ++ks)                                     \
        b_[ni][ks] = *(const s8v*)&sB[CUR][boff[ni][ks]];                                  \
    DN_PHASE(CUR, 0, ISSUE_A2((CUR) ^ 1, 1, nx1));                                         \
    /* P2 reads: b[2..3] */                                                                \
    DN_PHASE(CUR, 1, {                                                                     \
      _Pragma("unroll") for (int ni = 2; ni < 4; ++ni)                                     \
        _Pragma("unroll") for (int ks = 0; ks < 2; ++ks)                                   \
          b_[ni][ks] = *(const s8v*)&sB[CUR][boff[ni][ks]];                                \
      ISSUE_B2(sB, pB, (CUR) ^ 1, nx1); });                                                \
    DN_PHASE(CUR, 2, {});                                                                  \
    DN_PHASE(CUR, 3, { ISSUE_A2(CUR, 0, nx2); VMW2(); });                                  \
  } while (0)

  for (int t = 0; t < NKT; t += 2) {
    DN_HALF(0, t);
    DN_HALF(1, t + 1);
  }
#undef DN_HALF
#undef DN_PHASE

  int row0 = mtile * 256 + wm * 64;
  int col0 = n0 + wn * 64;
  const int* rowtok = meta + MI_ROWTOK;
  const float* roww = (const float*)(meta + MI_ROWW);
#pragma unroll
  for (int mi = 0; mi < 4; ++mi) {
#pragma unroll
    for (int r = 0; r < 4; ++r) {
      int row = row0 + mi * 16 + lg * 4 + r;
      int tok = rowtok[row];
      float w = roww[row];                    // 0 for pad rows
      float* orow = out + (size_t)tok * Hdim + col0 + lr;
#pragma unroll
      for (int ni = 0; ni < 4; ++ni)
        atomicAdd(orow + ni * 16, w * AC[mi][ni][r]);
    }
  }
}

extern "C" void kernel_launch(void* const* d_in, const int* in_sizes, int n_in,
                              void* d_out, int out_size, void* d_ws, size_t ws_size,
                              hipStream_t stream)
{
  (void)in_sizes; (void)n_in; (void)out_size; (void)ws_size;
  const float* x  = (const float*)d_in[0];
  const float* Wr = (const float*)d_in[1];
  const float* br = (const float*)d_in[2];
  const float* Wg = (const float*)d_in[3];
  const float* Wu = (const float*)d_in[4];
  const float* Wd = (const float*)d_in[5];
  float* out = (float*)d_out;
  float* logits = out + (size_t)NTOK * Hdim;        // output 1 region
  int* meta = (int*)d_ws;
  short* Xg   = (short*)((char*)d_ws + XG_OFF);
  short* WgT  = (short*)((char*)d_ws + WGT_OFF);
  short* WuT  = (short*)((char*)d_ws + WUT_OFF);
  short* WdT  = (short*)((char*)d_ws + WDT_OFF);    // aliases WgT
  short* Hbuf = (short*)((char*)d_ws + HB_OFF);

  hipMemsetAsync(d_out, 0, (size_t)NTOK * Hdim * sizeof(float), stream); // atomics accumulate
  hipMemsetAsync(d_ws, 0, META_ZERO_BYTES, stream);                      // counts + row tok/weight

  const int convBlocks = NEXP * (Idim / 64) * (Hdim / 64);               // 22528

  router_kernel <<<NTOK / 4, 256, 0, stream>>>(x, Wr, br, logits, meta);
  offsets_kernel<<<1, 256, 0, stream>>>(meta);
  scatter_kernel<<<NROW / 256, 256, 0, stream>>>(meta);
  gather_kernel <<<RCAP, 256, 0, stream>>>(x, Xg, meta);
  convT_kernel  <<<convBlocks, 256, 0, stream>>>(Wg, WgT, Hdim, Idim);
  convT_kernel  <<<convBlocks, 256, 0, stream>>>(Wu, WuT, Hdim, Idim);
  gateup_kernel <<<MT256 * (Idim / 128), 512, 0, stream>>>(Xg, WgT, WuT, Hbuf, meta);
  convT_kernel  <<<convBlocks, 256, 0, stream>>>(Wd, WdT, Idim, Hdim);   // after gateup (aliases WgT)
  down_kernel   <<<MT256 * (Hdim / 128), 512, 0, stream>>>(Hbuf, WdT, out, meta);
}

// Round 7
// 2256.302 us; speedup vs baseline: 1.0183x; 1.0183x over previous
//
#include <hip/hip_runtime.h>

// ---- problem constants ----
#define Hdim 2048
#define Idim 5632
#define NEXP 8
#define NTOK 8192          // B*S = 4*2048
#define NROW 16384         // NTOK * top_k
#define RCAP 18432         // 72 tiles * 256 (max padded rows, 256-align per expert)
#define MT256 72

// ---- workspace meta layout (int indices) ----
#define MI_NTILES   0      // number of 256-row M tiles
#define MI_TOTAL    1
#define MI_COUNT    2      // [8]
#define MI_CURSOR   10     // [8]
#define MI_OFF      18     // [9]
#define MI_TILEEXP  32     // [72]
#define MI_ROWTOK   128    // [18432] token index per gathered row
#define MI_ROWW     18560  // [18432] float weight per gathered row
#define MI_TOPKID   36992  // [16384]
#define MI_TOPKW    53376  // [16384] floats
#define META_ZERO_BYTES (36992u * 4u)   // zero counts..row_weight each call

// ---- workspace buffer layout (byte offsets) ----
#define XG_OFF   (1ull << 19)
#define WGT_OFF  (73ull  << 20)
#define WUT_OFF  (249ull << 20)
#define HB_OFF   (425ull << 20)
#define WDT_OFF  WGT_OFF   // WdT aliases WgT (conv_d runs after gateup)

typedef __attribute__((ext_vector_type(8))) short s8v;   // 8 bf16 = 4 VGPR
typedef __attribute__((ext_vector_type(4))) float f4v;   // MFMA acc

#define BAR()   asm volatile("s_barrier" ::: "memory")
#define VMW8()  asm volatile("s_waitcnt vmcnt(8)" ::: "memory")
#define LGKM0() asm volatile("s_waitcnt lgkmcnt(0)" ::: "memory")
#define PRIO1() __builtin_amdgcn_s_setprio(1)
#define PRIO0() __builtin_amdgcn_s_setprio(0)

__device__ __forceinline__ unsigned short f2bf(float f) {  // RNE
  unsigned int u = __float_as_uint(f);
  u += 0x7fffu + ((u >> 16) & 1u);
  return (unsigned short)(u >> 16);
}
__device__ __forceinline__ unsigned int pack2(float lo, float hi) { // truncate, 2 bf16 in 1 dword
  return (__float_as_uint(lo) >> 16) | (__float_as_uint(hi) & 0xffff0000u);
}
__device__ __forceinline__ void glds16(const short* gp, short* lp) {
  __builtin_amdgcn_global_load_lds(
      (const __attribute__((address_space(1))) void*)gp,
      (__attribute__((address_space(3))) void*)lp, 16, 0, 0);
}

// ---------------- router ----------------
__global__ __launch_bounds__(256) void router_kernel(
    const float* __restrict__ x, const float* __restrict__ Wr,
    const float* __restrict__ br, float* __restrict__ logits,
    int* __restrict__ meta)
{
  int wv = threadIdx.x >> 6, lane = threadIdx.x & 63;
  int t = blockIdx.x * 4 + wv;
  const float* xr = x + (size_t)t * Hdim;
  float acc[8];
#pragma unroll
  for (int e = 0; e < 8; ++e) acc[e] = 0.f;
  for (int i = lane; i < Hdim; i += 64) {
    float xv = xr[i];
    const float4 w0 = *(const float4*)(Wr + (size_t)i * 8);
    const float4 w1 = *(const float4*)(Wr + (size_t)i * 8 + 4);
    acc[0] += xv * w0.x; acc[1] += xv * w0.y; acc[2] += xv * w0.z; acc[3] += xv * w0.w;
    acc[4] += xv * w1.x; acc[5] += xv * w1.y; acc[6] += xv * w1.z; acc[7] += xv * w1.w;
  }
#pragma unroll
  for (int off = 32; off > 0; off >>= 1)
#pragma unroll
    for (int e = 0; e < 8; ++e) acc[e] += __shfl_down(acc[e], off);
  if (lane == 0) {
    float l[8];
#pragma unroll
    for (int e = 0; e < 8; ++e) { l[e] = acc[e] + br[e]; logits[(size_t)t * 8 + e] = l[e]; }
    int i1 = 0;
#pragma unroll
    for (int e = 1; e < 8; ++e) if (l[e] > l[i1]) i1 = e;
    int i2 = -1;
#pragma unroll
    for (int e = 0; e < 8; ++e) if (e != i1 && (i2 < 0 || l[e] > l[i2])) i2 = e;
    float p2 = __expf(l[i2] - l[i1]);
    float s = 1.f + p2;
    meta[MI_TOPKID + t * 2]     = i1;
    meta[MI_TOPKID + t * 2 + 1] = i2;
    float* tw = (float*)(meta + MI_TOPKW);
    tw[t * 2] = 1.f / s; tw[t * 2 + 1] = p2 / s;
    atomicAdd(&meta[MI_COUNT + i1], 1);
    atomicAdd(&meta[MI_COUNT + i2], 1);
  }
}

// ---------------- offsets: 256-aligned expert segments ----------------
__global__ void offsets_kernel(int* __restrict__ meta)
{
  __shared__ int soff[9];
  if (threadIdx.x == 0) {
    int off = 0;
#pragma unroll
    for (int e = 0; e < 8; ++e) {
      soff[e] = off;
      meta[MI_OFF + e] = off;
      meta[MI_CURSOR + e] = off;
      int c = meta[MI_COUNT + e];
      off += (c + 255) & ~255;
    }
    soff[8] = off;
    meta[MI_OFF + 8] = off;
    meta[MI_TOTAL] = off;
    meta[MI_NTILES] = off >> 8;
  }
  __syncthreads();
  int tile = threadIdx.x;
  if (tile < MT256) {
    int r = tile << 8;
    int e = 7;
    for (int q = 7; q >= 0; --q) if (r < soff[q + 1]) e = q;
    meta[MI_TILEEXP + tile] = e;
  }
}

// ---------------- scatter ----------------
__global__ __launch_bounds__(256) void scatter_kernel(int* __restrict__ meta)
{
  int idx = blockIdx.x * 256 + threadIdx.x;           // < 16384
  int e = meta[MI_TOPKID + idx];
  float w = ((const float*)(meta + MI_TOPKW))[idx];
  int pos = atomicAdd(&meta[MI_CURSOR + e], 1);
  meta[MI_ROWTOK + pos] = idx >> 1;
  ((float*)(meta + MI_ROWW))[pos] = w;
}

// ---------------- gather: x rows -> bf16 Xg in expert order ----------------
__global__ __launch_bounds__(256) void gather_kernel(
    const float* __restrict__ x, short* __restrict__ Xg,
    const int* __restrict__ meta)
{
  int r = blockIdx.x;
  int tok = meta[MI_ROWTOK + r];                       // 0 for pad rows (weight 0)
  int i = threadIdx.x * 8;
  const float* src = x + (size_t)tok * Hdim + i;
  float4 a = *(const float4*)src;
  float4 b = *(const float4*)(src + 4);
  union { s8v v; unsigned short us[8]; } o;
  o.us[0] = f2bf(a.x); o.us[1] = f2bf(a.y); o.us[2] = f2bf(a.z); o.us[3] = f2bf(a.w);
  o.us[4] = f2bf(b.x); o.us[5] = f2bf(b.y); o.us[6] = f2bf(b.z); o.us[7] = f2bf(b.w);
  *(s8v*)(Xg + (size_t)r * Hdim + i) = o.v;
}

// ---------------- transpose-convert: T[e][n][k] (bf16) = W[e][k][n] (fp32) ----------------
__global__ __launch_bounds__(256) void convT_kernel(
    const float* __restrict__ W, short* __restrict__ T, int K, int N)
{
  __shared__ float lds[64][65];
  int ntn = N >> 6, ntk = K >> 6;
  int per_e = ntn * ntk;
  int e = blockIdx.x / per_e;
  int r = blockIdx.x % per_e;
  int tn = r % ntn, tk = r / ntn;
  const float* We = W + (size_t)e * K * N;
  short* Te = T + (size_t)e * K * N;
  int n0 = tn << 6, k0 = tk << 6;
  int tid = threadIdx.x;
  int c = tid & 63, rr = tid >> 6;
#pragma unroll
  for (int i = 0; i < 16; ++i) {
    int k = i * 4 + rr;
    lds[c][k] = We[(size_t)(k0 + k) * N + n0 + c];
  }
  __syncthreads();
  int kp = tid & 31, nb = tid >> 5;
#pragma unroll
  for (int i = 0; i < 8; ++i) {
    int n = i * 8 + nb;
    float2 f = *(const float2*)&lds[n][kp * 2];
    unsigned int u = pack2(f.x, f.y);
    *(unsigned int*)((char*)Te + ((size_t)(n0 + n) * K + k0) * 2 + kp * 4) = u;
  }
}

// ======== 8-phase GEMMs with DERIVED WAITS: BM=256, BK=64, 512 threads (8 waves 4Mx2N) ====
// All 8 staging loads for tile t+2 issue clustered at P4(t) into buf[t&1] (reads certified
// by lgkmcnt(0) before P3's closing barrier); vmcnt(8) then retires tile t+1's loads,
// issued 4 phases (~2800cy) earlier -> HBM latency fully hidden. In-flight = 16 loads.
// LDS row-major [row][64] bf16, XOR 16B-slot swizzle (write side pre-swizzled on the
// GLOBAL source per rule #21; read side swizzles the ds_read offset).

// stage one 64-row round r: global pX + r*64*stride, LDS arr[buf][r*4096 + ldst]
#define STG(arr, pX, buf, r, kk) \
  glds16((pX) + (size_t)(r) * 64 * strideA + (kk), &arr[(buf)][(r) * 4096 + ldst])

// ---------------- pass A: h = silu(Xg@Wg[e]) * (Xg@Wu[e]) -> bf16 Hbuf ----------------
__global__ __launch_bounds__(512, 2) void gateup_kernel(
    const short* __restrict__ Xg, const short* __restrict__ WgT,
    const short* __restrict__ WuT, short* __restrict__ Hbuf,
    const int* __restrict__ meta)
{
  const int NT = Idim / 128;                 // 44
  int wg = (blockIdx.x & 7) * (MT256 / 8 * NT) + (blockIdx.x >> 3);  // XCD-bijective
  int chunk = wg / (8 * NT);
  int rem   = wg % (8 * NT);
  int mtile = chunk * 8 + (rem & 7);
  int ntile = rem >> 3;
  if (mtile >= meta[MI_NTILES]) return;
  int e = meta[MI_TILEEXP + mtile];
  int n0 = ntile * 128;
  const size_t strideA = Hdim;

  __shared__ short sA[2][16384];             // 256 x 64 (4 rounds)
  __shared__ short sG[2][8192];              // 128 x 64 (2 rounds)
  __shared__ short sU[2][8192];

  int tid = threadIdx.x;
  int lane = tid & 63, wv = tid >> 6;
  int wm = wv >> 1, wn = wv & 1;
  int lr = lane & 15, lg = lane >> 4;
  int ldst = wv * 512;                       // wave-uniform LDS dest (shorts)

  int srow = tid >> 3;
  int kc = ((tid & 7) ^ (srow & 7)) * 8;     // pre-swizzled global k-slot
  const short* pA = Xg  + (size_t)(mtile * 256) * Hdim + (size_t)srow * Hdim + kc;
  const short* pG = WgT + (size_t)e * Idim * Hdim + (size_t)(n0 + srow) * Hdim + kc;
  const short* pU = WuT + (size_t)e * Idim * Hdim + (size_t)(n0 + srow) * Hdim + kc;

  int aoff[4][2], boff[4][2];
#pragma unroll
  for (int mi = 0; mi < 4; ++mi) {
    int R = wm * 64 + mi * 16 + lr;
#pragma unroll
    for (int ks = 0; ks < 2; ++ks) aoff[mi][ks] = R * 64 + (((ks * 4 + lg) ^ (R & 7)) << 3);
  }
#pragma unroll
  for (int ni = 0; ni < 4; ++ni) {
    int R = wn * 64 + ni * 16 + lr;
#pragma unroll
    for (int ks = 0; ks < 2; ++ks) boff[ni][ks] = R * 64 + (((ks * 4 + lg) ^ (R & 7)) << 3);
  }

  f4v AG[4][4], AU[4][4];
  f4v z = {0.f, 0.f, 0.f, 0.f};
#pragma unroll
  for (int a1 = 0; a1 < 4; ++a1)
#pragma unroll
    for (int b1 = 0; b1 < 4; ++b1) { AG[a1][b1] = z; AU[a1][b1] = z; }

  const int NKT = Hdim / 64;                 // 32 (even)

#define GU_STAGE(buf, kt) do { size_t kk_ = (size_t)(kt) * 64;  \
    STG(sA, pA, buf, 0, kk_); STG(sA, pA, buf, 1, kk_);         \
    STG(sA, pA, buf, 2, kk_); STG(sA, pA, buf, 3, kk_);         \
    STG(sG, pG, buf, 0, kk_); STG(sG, pG, buf, 1, kk_);         \
    STG(sU, pU, buf, 0, kk_); STG(sU, pU, buf, 1, kk_); } while (0)

  // prologue: tiles 0,1 fully staged; vmcnt(8) -> tile0 landed
  GU_STAGE(0, 0); GU_STAGE(1, 1);
  VMW8(); BAR();

#define GU_TILE(CUR, T)                                                                    \
  do {                                                                                     \
    int nx2 = (T) + 2; if (nx2 >= NKT) nx2 -= NKT;                                         \
    s8v a_[4][2], g0_[2][2], g1_[2][2], u0_[2][2], u1_[2][2];                              \
    /* P1: read a + g0 */                                                                  \
    _Pragma("unroll") for (int mi = 0; mi < 4; ++mi)                                       \
      _Pragma("unroll") for (int ks = 0; ks < 2; ++ks)                                     \
        a_[mi][ks] = *(const s8v*)&sA[CUR][aoff[mi][ks]];                                  \
    _Pragma("unroll") for (int ni = 0; ni < 2; ++ni)                                       \
      _Pragma("unroll") for (int ks = 0; ks < 2; ++ks)                                     \
        g0_[ni][ks] = *(const s8v*)&sG[CUR][boff[ni][ks]];                                 \
    BAR(); PRIO1();                                                                        \
    _Pragma("unroll") for (int mi = 0; mi < 4; ++mi)                                       \
      _Pragma("unroll") for (int ni = 0; ni < 2; ++ni)                                     \
        _Pragma("unroll") for (int ks = 0; ks < 2; ++ks)                                   \
          AG[mi][ni] = __builtin_amdgcn_mfma_f32_16x16x32_bf16(a_[mi][ks], g0_[ni][ks],    \
                                                               AG[mi][ni], 0, 0, 0);       \
    PRIO0(); BAR();                                                                        \
    /* P2: read g1 + u0 */                                                                 \
    _Pragma("unroll") for (int ni = 0; ni < 2; ++ni)                                       \
      _Pragma("unroll") for (int ks = 0; ks < 2; ++ks) {                                   \
        g1_[ni][ks] = *(const s8v*)&sG[CUR][boff[2 + ni][ks]];                             \
        u0_[ni][ks] = *(const s8v*)&sU[CUR][boff[ni][ks]];                                 \
      }                                                                                    \
    BAR(); PRIO1();                                                                        \
    _Pragma("unroll") for (int mi = 0; mi < 4; ++mi)                                       \
      _Pragma("unroll") for (int ni = 0; ni < 2; ++ni)                                     \
        _Pragma("unroll") for (int ks = 0; ks < 2; ++ks)                                   \
          AG[mi][2 + ni] = __builtin_amdgcn_mfma_f32_16x16x32_bf16(a_[mi][ks], g1_[ni][ks],\
                                                                   AG[mi][2 + ni], 0, 0, 0);\
    PRIO0(); BAR();                                                                        \
    /* P3: read u1; lgkm(0) before closing bar certifies ALL tile reads cross-wave */      \
    _Pragma("unroll") for (int ni = 0; ni < 2; ++ni)                                       \
      _Pragma("unroll") for (int ks = 0; ks < 2; ++ks)                                     \
        u1_[ni][ks] = *(const s8v*)&sU[CUR][boff[2 + ni][ks]];                             \
    BAR(); PRIO1();                                                                        \
    _Pragma("unroll") for (int mi = 0; mi < 4; ++mi)                                       \
      _Pragma("unroll") for (int ni = 0; ni < 2; ++ni)                                     \
        _Pragma("unroll") for (int ks = 0; ks < 2; ++ks)                                   \
          AU[mi][ni] = __builtin_amdgcn_mfma_f32_16x16x32_bf16(a_[mi][ks], u0_[ni][ks],    \
                                                               AU[mi][ni], 0, 0, 0);       \
    PRIO0(); LGKM0(); BAR();                                                               \
    /* P4: stage tile t+2 into CUR; vmcnt(8) retires tile t+1 (issued 4 phases ago) */     \
    GU_STAGE(CUR, nx2);                                                                    \
    VMW8();                                                                                \
    BAR(); PRIO1();                                                                        \
    _Pragma("unroll") for (int mi = 0; mi < 4; ++mi)                                       \
      _Pragma("unroll") for (int ni = 0; ni < 2; ++ni)                                     \
        _Pragma("unroll") for (int ks = 0; ks < 2; ++ks)                                   \
          AU[mi][2 + ni] = __builtin_amdgcn_mfma_f32_16x16x32_bf16(a_[mi][ks], u1_[ni][ks],\
                                                                   AU[mi][2 + ni], 0, 0, 0);\
    PRIO0(); BAR();                                                                        \
  } while (0)

  for (int t = 0; t < NKT; t += 2) {
    GU_TILE(0, t);
    GU_TILE(1, t + 1);
  }
#undef GU_TILE
#undef GU_STAGE

  // epilogue: h = silu(g)*u -> bf16  (C/D: col=lane&15, row=(lane>>4)*4+r)
  int row0 = mtile * 256 + wm * 64;
  int col0 = n0 + wn * 64;
#pragma unroll
  for (int mi = 0; mi < 4; ++mi) {
#pragma unroll
    for (int ni = 0; ni < 4; ++ni) {
      int col = col0 + ni * 16 + lr;
#pragma unroll
      for (int r = 0; r < 4; ++r) {
        int row = row0 + mi * 16 + lg * 4 + r;
        float g = AG[mi][ni][r], u = AU[mi][ni][r];
        float h = g / (1.f + __expf(-g)) * u;
        Hbuf[(size_t)row * Idim + col] = (short)f2bf(h);
      }
    }
  }
}

// ---------------- pass B: y = Hbuf@Wd[e]; out[token] += w*y (atomic) ----------------
// BN=256: 8 waves 4Mx2N, per-wave 64x128, same 4-phase derived-wait template.
__global__ __launch_bounds__(512, 2) void down_kernel(
    const short* __restrict__ Hbuf, const short* __restrict__ WdT,
    float* __restrict__ out, const int* __restrict__ meta)
{
  const int NT = Hdim / 256;                 // 8
  int wg = (blockIdx.x & 7) * (MT256 / 8 * NT) + (blockIdx.x >> 3);
  int chunk = wg / (8 * NT);
  int rem   = wg % (8 * NT);
  int mtile = chunk * 8 + (rem & 7);
  int ntile = rem >> 3;
  if (mtile >= meta[MI_NTILES]) return;
  int e = meta[MI_TILEEXP + mtile];
  int n0 = ntile * 256;
  const size_t strideA = Idim;

  __shared__ short sA[2][16384];             // 256 x 64
  __shared__ short sB[2][16384];             // 256 x 64

  int tid = threadIdx.x;
  int lane = tid & 63, wv = tid >> 6;
  int wm = wv >> 1, wn = wv & 1;
  int lr = lane & 15, lg = lane >> 4;
  int ldst = wv * 512;

  int srow = tid >> 3;
  int kc = ((tid & 7) ^ (srow & 7)) * 8;
  const short* pA = Hbuf + (size_t)(mtile * 256) * Idim + (size_t)srow * Idim + kc;
  const short* pB = WdT  + (size_t)e * Hdim * Idim + (size_t)(n0 + srow) * Idim + kc;

  int aoff[4][2], boff[8][2];
#pragma unroll
  for (int mi = 0; mi < 4; ++mi) {
    int R = wm * 64 + mi * 16 + lr;
#pragma unroll
    for (int ks = 0; ks < 2; ++ks) aoff[mi][ks] = R * 64 + (((ks * 4 + lg) ^ (R & 7)) << 3);
  }
#pragma unroll
  for (int ni = 0; ni < 8; ++ni) {
    int R = wn * 128 + ni * 16 + lr;
#pragma unroll
    for (int ks = 0; ks < 2; ++ks) boff[ni][ks] = R * 64 + (((ks * 4 + lg) ^ (R & 7)) << 3);
  }

  f4v AC[4][8];
  f4v z = {0.f, 0.f, 0.f, 0.f};
#pragma unroll
  for (int a1 = 0; a1 < 4; ++a1)
#pragma unroll
    for (int b1 = 0; b1 < 8; ++b1) AC[a1][b1] = z;

  const int NKT = Idim / 64;                 // 88 (even)

#define DN_STAGE(buf, kt) do { size_t kk_ = (size_t)(kt) * 64;  \
    STG(sA, pA, buf, 0, kk_); STG(sA, pA, buf, 1, kk_);         \
    STG(sA, pA, buf, 2, kk_); STG(sA, pA, buf, 3, kk_);         \
    STG(sB, pB, buf, 0, kk_); STG(sB, pB, buf, 1, kk_);         \
    STG(sB, pB, buf, 2, kk_); STG(sB, pB, buf, 3, kk_); } while (0)

  DN_STAGE(0, 0); DN_STAGE(1, 1);
  VMW8(); BAR();

#define DN_MFMA(NI0)                                                                       \
    BAR(); PRIO1();                                                                        \
    _Pragma("unroll") for (int mi = 0; mi < 4; ++mi)                                       \
      _Pragma("unroll") for (int nj = 0; nj < 2; ++nj)                                     \
        _Pragma("unroll") for (int ks = 0; ks < 2; ++ks)                                   \
          AC[mi][(NI0) + nj] = __builtin_amdgcn_mfma_f32_16x16x32_bf16(                    \
              a_[mi][ks], b_[(NI0) + nj][ks], AC[mi][(NI0) + nj], 0, 0, 0);                \
    PRIO0()

#define DN_TILE(CUR, T)                                                                    \
  do {                                                                                     \
    int nx2 = (T) + 2; if (nx2 >= NKT) nx2 -= NKT;                                         \
    s8v a_[4][2], b_[8][2];                                                                \
    /* P1: read a + b01 */                                                                 \
    _Pragma("unroll") for (int mi = 0; mi < 4; ++mi)                                       \
      _Pragma("unroll") for (int ks = 0; ks < 2; ++ks)                                     \
        a_[mi][ks] = *(const s8v*)&sA[CUR][aoff[mi][ks]];                                  \
    _Pragma("unroll") for (int ni = 0; ni < 2; ++ni)                                       \
      _Pragma("unroll") for (int ks = 0; ks < 2; ++ks)                                     \
        b_[ni][ks] = *(const s8v*)&sB[CUR][boff[ni][ks]];                                  \
    DN_MFMA(0); BAR();                                                                     \
    /* P2: read b23 */                                                                     \
    _Pragma("unroll") for (int ni = 2; ni < 4; ++ni)                                       \
      _Pragma("unroll") for (int ks = 0; ks < 2; ++ks)                                     \
        b_[ni][ks] = *(const s8v*)&sB[CUR][boff[ni][ks]];                                  \
    DN_MFMA(2); BAR();                                                                     \
    /* P3: read b45 + b67; lgkm(0) before closing bar */                                   \
    _Pragma("unroll") for (int ni = 4; ni < 8; ++ni)                                       \
      _Pragma("unroll") for (int ks = 0; ks < 2; ++ks)                                     \
        b_[ni][ks] = *(const s8v*)&sB[CUR][boff[ni][ks]];                                  \
    DN_MFMA(4); LGKM0(); BAR();                                                            \
    /* P4: stage t+2; counted wait */                                                      \
    DN_STAGE(CUR, nx2);                                                                    \
    VMW8();                                                                                \
    DN_MFMA(6); BAR();                                                                     \
  } while (0)

  for (int t = 0; t < NKT; t += 2) {
    DN_TILE(0, t);
    DN_TILE(1, t + 1);
  }
#undef DN_TILE
#undef DN_MFMA
#undef DN_STAGE

  int row0 = mtile * 256 + wm * 64;
  int col0 = n0 + wn * 128;
  const int* rowtok = meta + MI_ROWTOK;
  const float* roww = (const float*)(meta + MI_ROWW);
#pragma unroll
  for (int mi = 0; mi < 4; ++mi) {
#pragma unroll
    for (int r = 0; r < 4; ++r) {
      int row = row0 + mi * 16 + lg * 4 + r;
      int tok = rowtok[row];
      float w = roww[row];                    // 0 for pad rows
      float* orow = out + (size_t)tok * Hdim + col0 + lr;
#pragma unroll
      for (int ni = 0; ni < 8; ++ni)
        atomicAdd(orow + ni * 16, w * AC[mi][ni][r]);
    }
  }
}

extern "C" void kernel_launch(void* const* d_in, const int* in_sizes, int n_in,
                              void* d_out, int out_size, void* d_ws, size_t ws_size,
                              hipStream_t stream)
{
  (void)in_sizes; (void)n_in; (void)out_size; (void)ws_size;
  const float* x  = (const float*)d_in[0];
  const float* Wr = (const float*)d_in[1];
  const float* br = (const float*)d_in[2];
  const float* Wg = (const float*)d_in[3];
  const float* Wu = (const float*)d_in[4];
  const float* Wd = (const float*)d_in[5];
  float* out = (float*)d_out;
  float* logits = out + (size_t)NTOK * Hdim;        // output 1 region
  int* meta = (int*)d_ws;
  short* Xg   = (short*)((char*)d_ws + XG_OFF);
  short* WgT  = (short*)((char*)d_ws + WGT_OFF);
  short* WuT  = (short*)((char*)d_ws + WUT_OFF);
  short* WdT  = (short*)((char*)d_ws + WDT_OFF);    // aliases WgT
  short* Hbuf = (short*)((char*)d_ws + HB_OFF);

  hipMemsetAsync(d_out, 0, (size_t)NTOK * Hdim * sizeof(float), stream); // atomics accumulate
  hipMemsetAsync(d_ws, 0, META_ZERO_BYTES, stream);                      // counts + row tok/weight

  const int convBlocks = NEXP * (Idim / 64) * (Hdim / 64);               // 22528

  router_kernel <<<NTOK / 4, 256, 0, stream>>>(x, Wr, br, logits, meta);
  offsets_kernel<<<1, 256, 0, stream>>>(meta);
  scatter_kernel<<<NROW / 256, 256, 0, stream>>>(meta);
  gather_kernel <<<RCAP, 256, 0, stream>>>(x, Xg, meta);
  convT_kernel  <<<convBlocks, 256, 0, stream>>>(Wg, WgT, Hdim, Idim);
  convT_kernel  <<<convBlocks, 256, 0, stream>>>(Wu, WuT, Hdim, Idim);
  gateup_kernel <<<MT256 * (Idim / 128), 512, 0, stream>>>(Xg, WgT, WuT, Hbuf, meta);
  convT_kernel  <<<convBlocks, 256, 0, stream>>>(Wd, WdT, Idim, Hdim);   // after gateup (aliases WgT)
  down_kernel   <<<MT256 * (Hdim / 256), 512, 0, stream>>>(Hbuf, WdT, out, meta);
}